// Round 19
// baseline (536.168 us; speedup 1.0000x reference)
//
#include <hip/hip_runtime.h>
#include <cstdint>
#include <cstddef>

// ---------------------------------------------------------------------------
// AKT-style 6-layer transformer forward on MI355X (gfx950).  Round 19:
//  - attention: __launch_bounds__(512, 6) — forces VGPR <= 85 so the R18
//    parity-split's 3 blocks/CU (6 waves/SIMD) actually become resident.
//    Single-variable experiment; everything else R18-bit-identical
//    (passed, 519.1 us).
// ---------------------------------------------------------------------------

#define AS1 __attribute__((address_space(1)))
#define AS3 __attribute__((address_space(3)))

typedef __bf16 bf16;
typedef __bf16 bf16x8 __attribute__((ext_vector_type(8)));
typedef __bf16 bf16x4 __attribute__((ext_vector_type(4)));
typedef __bf16 bf16x2 __attribute__((ext_vector_type(2)));
typedef float  f32x4  __attribute__((ext_vector_type(4)));
typedef float  f32x16 __attribute__((ext_vector_type(16)));
typedef unsigned int u32;

static constexpr int Mc = 32 * 512; // 16384 rows

// ---------------------------------------------------------------- converts
__global__ void cvt_copy2_kernel(const float* __restrict__ s0, float* __restrict__ da32,
                                 bf16* __restrict__ da16, const float* __restrict__ s1,
                                 float* __restrict__ db32, bf16* __restrict__ db16, int n4) {
  const float* s = blockIdx.y ? s1 : s0;
  float* d32 = blockIdx.y ? db32 : da32;
  bf16* d16 = blockIdx.y ? db16 : da16;
  int i = blockIdx.x * blockDim.x + threadIdx.x;
  if (i < n4) {
    float4 v = ((const float4*)s)[i];
    ((float4*)d32)[i] = v;
    bf16x4 hx = {(bf16)v.x, (bf16)v.y, (bf16)v.z, (bf16)v.w};
    ((bf16x4*)d16)[i] = hx;
  }
}

// Tiled transpose+cvt for all 5 weights: W[K,N] fp32 -> Wt[N,K] bf16.
__global__ __launch_bounds__(256) void transpose_cvt_all(
    const float* __restrict__ Wk, const float* __restrict__ Wv, const float* __restrict__ Wo,
    const float* __restrict__ W1, const float* __restrict__ W2,
    bf16* __restrict__ Wkt, bf16* __restrict__ Wvt, bf16* __restrict__ Wot,
    bf16* __restrict__ W1t, bf16* __restrict__ W2t) {
  int z = blockIdx.z;
  int layer = z % 6, w = z / 6;
  const float* src; bf16* dst; int K, N;
  switch (w) {
    case 0: src = Wk; dst = Wkt; K = 256; N = 256; break;
    case 1: src = Wv; dst = Wvt; K = 256; N = 256; break;
    case 2: src = Wo; dst = Wot; K = 256; N = 256; break;
    case 3: src = W1; dst = W1t; K = 256; N = 1024; break;
    default: src = W2; dst = W2t; K = 1024; N = 256; break;
  }
  int k0 = blockIdx.x * 64, n0 = blockIdx.y * 64;
  if (k0 >= K || n0 >= N) return;
  src += (size_t)layer * K * N;
  dst += (size_t)layer * K * N;
  __shared__ bf16 t[64][68];
  int tid = threadIdx.x;
  int rr = tid >> 4;
  int c4 = (tid & 15) * 4;
#pragma unroll
  for (int p = 0; p < 4; ++p) {
    int k = rr + p * 16;
    float4 v = *(const float4*)(src + (size_t)(k0 + k) * N + n0 + c4);
    t[c4 + 0][k] = (bf16)v.x;
    t[c4 + 1][k] = (bf16)v.y;
    t[c4 + 2][k] = (bf16)v.z;
    t[c4 + 3][k] = (bf16)v.w;
  }
  __syncthreads();
#pragma unroll
  for (int p = 0; p < 4; ++p) {
    int nl = rr + p * 16;
    bf16x4 o4 = *(const bf16x4*)&t[nl][c4];
    *(bf16x4*)(dst + (size_t)(n0 + nl) * K + k0 + c4) = o4;
  }
}

// ---------------------------------------------------------------- GEMM (plain)
template <int RELU, typename OUT_T>
__device__ __forceinline__ void gemm_body(
    const bf16* __restrict__ A, const bf16* __restrict__ Bt,
    const float* __restrict__ bias, OUT_T* __restrict__ C,
    int K, int N, int m0, int n0, bf16* As, bf16* Bs) {
  const int tid = threadIdx.x;
  const int lane = tid & 63;
  const int wid = tid >> 6;
  const int wm = (wid >> 1) * 64;
  const int wn = (wid & 1) * 64;
  f32x4 acc[4][4] = {};

  const int o1 = wid * 1024 + lane * 16;
  const int o2 = o1 + 4096;
  const int r1 = o1 >> 6, c1 = o1 & 63;
  const int r2 = o2 >> 6, c2 = o2 & 63;
  const char* Ab = (const char*)A;
  const char* Bb = (const char*)Bt;
  const size_t stride = (size_t)K * 2;

  auto stage_panel = [&](int panel, int kk) {
    const char* a1 = Ab + (size_t)(m0 + r1) * stride + (size_t)kk * 2 + c1;
    const char* a2 = Ab + (size_t)(m0 + r2) * stride + (size_t)kk * 2 + c2;
    const char* b1 = Bb + (size_t)(n0 + r1) * stride + (size_t)kk * 2 + c1;
    const char* b2 = Bb + (size_t)(n0 + r2) * stride + (size_t)kk * 2 + c2;
    char* ad = (char*)As + panel * 8192 + wid * 1024;
    char* bd = (char*)Bs + panel * 8192 + wid * 1024;
    __builtin_amdgcn_global_load_lds((const AS1 u32*)a1, (AS3 u32*)ad, 16, 0, 0);
    __builtin_amdgcn_global_load_lds((const AS1 u32*)a2, (AS3 u32*)(ad + 4096), 16, 0, 0);
    __builtin_amdgcn_global_load_lds((const AS1 u32*)b1, (AS3 u32*)bd, 16, 0, 0);
    __builtin_amdgcn_global_load_lds((const AS1 u32*)b2, (AS3 u32*)(bd + 4096), 16, 0, 0);
  };

  stage_panel(0, 0);
  stage_panel(1, 32);
  asm volatile("s_waitcnt vmcnt(0)" ::: "memory");
  __syncthreads();

  int cur = 0;
  for (int k0 = 0; k0 < K; k0 += 64) {
    if (k0 + 64 < K) {
      stage_panel((cur ^ 1) * 2, k0 + 64);
      stage_panel((cur ^ 1) * 2 + 1, k0 + 96);
    }
    const int rr = lane & 15;
    const int g8 = (lane >> 4) * 8;
#pragma unroll
    for (int s = 0; s < 2; ++s) {
      const int base = (cur * 2 + s) * 4096;
      bf16x8 af[4], bfr[4];
#pragma unroll
      for (int i = 0; i < 4; ++i) {
        af[i]  = *(const bf16x8*)&As[base + (wm + i * 16 + rr) * 32 + g8];
        bfr[i] = *(const bf16x8*)&Bs[base + (wn + i * 16 + rr) * 32 + g8];
      }
#pragma unroll
      for (int mi = 0; mi < 4; ++mi)
#pragma unroll
        for (int ni = 0; ni < 4; ++ni)
          acc[mi][ni] = __builtin_amdgcn_mfma_f32_16x16x32_bf16(af[mi], bfr[ni], acc[mi][ni], 0, 0, 0);
    }
    asm volatile("s_waitcnt vmcnt(0)" ::: "memory");
    __syncthreads();
    cur ^= 1;
  }

  const int rr = lane & 15;
  const int g4 = (lane >> 4) * 4;
  float bv[4];
#pragma unroll
  for (int ni = 0; ni < 4; ++ni) bv[ni] = bias[n0 + wn + ni * 16 + rr];
#pragma unroll
  for (int mi = 0; mi < 4; ++mi)
#pragma unroll
    for (int ni = 0; ni < 4; ++ni)
#pragma unroll
      for (int r = 0; r < 4; ++r) {
        float v = acc[mi][ni][r] + bv[ni];
        if (RELU) v = fmaxf(v, 0.f);
        int row = m0 + wm + mi * 16 + g4 + r;
        int col = n0 + wn + ni * 16 + rr;
        C[(size_t)row * N + col] = (OUT_T)v;
      }
}

__global__ __launch_bounds__(256) void gemm_kv_kernel(
    const bf16* __restrict__ A0, const bf16* __restrict__ Bt0,
    const float* __restrict__ b0, bf16* __restrict__ C0,
    const bf16* __restrict__ A1, const bf16* __restrict__ Bt1,
    const float* __restrict__ b1, bf16* __restrict__ C1, int K, int N) {
  __shared__ bf16 As[4 * 4096];
  __shared__ bf16 Bs[4 * 4096];
  int sel = blockIdx.y >> 1;
  gemm_body<0, bf16>(sel ? A1 : A0, sel ? Bt1 : Bt0, sel ? b1 : b0, sel ? C1 : C0,
                     K, N, blockIdx.x * 128, (blockIdx.y & 1) * 128, As, Bs);
}

// ---------------------------------------------------------------- GEMM + LN (R9 32-row)
template <int KSZ>
__global__ __launch_bounds__(512, 4) void gemm_ln_kernel(
    const bf16* __restrict__ A, const bf16* __restrict__ Bt,
    const float* __restrict__ bias, const float* __restrict__ resid,
    const float* __restrict__ lns, const float* __restrict__ lnb,
    float* __restrict__ out32, bf16* __restrict__ out16) {
  __shared__ bf16 As[2 * 32 * 32];
  __shared__ bf16 Bs[2 * 256 * 32];
  __shared__ float wsum[8][16][2];
  __shared__ float stats[32][2];
  const int tid = threadIdx.x, lane = tid & 63, wid = tid >> 6;
  const int m0 = blockIdx.x * 32;
  const int wr = wid >> 2, wc = wid & 3;
  f32x4 acc[4] = {};
  const char* Ab = (const char*)A;
  const char* Bb = (const char*)Bt;
  const size_t stride = (size_t)KSZ * 2;

  auto stage = [&](int buf, int kk) {
    if (wid < 2) {
      int off = wid * 1024 + lane * 16;
      const char* a1 = Ab + (size_t)(m0 + (off >> 6)) * stride + (size_t)kk * 2 + (off & 63);
      __builtin_amdgcn_global_load_lds((const AS1 u32*)a1,
                                       (AS3 u32*)((char*)As + buf * 2048 + wid * 1024), 16, 0, 0);
    }
    int off1 = wid * 2048 + lane * 16;
    int off2 = off1 + 1024;
    const char* b1 = Bb + (size_t)(off1 >> 6) * stride + (size_t)kk * 2 + (off1 & 63);
    const char* b2 = Bb + (size_t)(off2 >> 6) * stride + (size_t)kk * 2 + (off2 & 63);
    char* bd = (char*)Bs + buf * 16384 + wid * 2048;
    __builtin_amdgcn_global_load_lds((const AS1 u32*)b1, (AS3 u32*)bd, 16, 0, 0);
    __builtin_amdgcn_global_load_lds((const AS1 u32*)b2, (AS3 u32*)(bd + 1024), 16, 0, 0);
  };

  stage(0, 0);
  asm volatile("s_waitcnt vmcnt(0)" ::: "memory");
  __syncthreads();

  int cur = 0;
  for (int k0 = 0; k0 < KSZ; k0 += 32) {
    if (k0 + 32 < KSZ) stage(cur ^ 1, k0 + 32);
    const int rr = lane & 15, g8 = (lane >> 4) * 8;
    bf16x8 af = *(const bf16x8*)&As[cur * 1024 + (wr * 16 + rr) * 32 + g8];
    bf16x8 bfr[4];
#pragma unroll
    for (int ni = 0; ni < 4; ++ni)
      bfr[ni] = *(const bf16x8*)&Bs[cur * 8192 + (wc * 64 + ni * 16 + rr) * 32 + g8];
#pragma unroll
    for (int ni = 0; ni < 4; ++ni)
      acc[ni] = __builtin_amdgcn_mfma_f32_16x16x32_bf16(af, bfr[ni], acc[ni], 0, 0, 0);
    asm volatile("s_waitcnt vmcnt(0)" ::: "memory");
    __syncthreads();
    cur ^= 1;
  }

  const int rr = lane & 15, g4 = (lane >> 4) * 4;
  float bv[4], scv[4], biv[4];
  int col[4];
#pragma unroll
  for (int ni = 0; ni < 4; ++ni) {
    col[ni] = wc * 64 + ni * 16 + rr;
    bv[ni] = bias[col[ni]];
    scv[ni] = lns[col[ni]];
    biv[ni] = lnb[col[ni]];
  }
  float v[4][4];
#pragma unroll
  for (int r = 0; r < 4; ++r) {
    int grow = m0 + wr * 16 + g4 + r;
#pragma unroll
    for (int ni = 0; ni < 4; ++ni)
      v[ni][r] = acc[ni][r] + bv[ni] + resid[(size_t)grow * 256 + col[ni]];
  }
#pragma unroll
  for (int r = 0; r < 4; ++r) {
    float s1 = (v[0][r] + v[1][r]) + (v[2][r] + v[3][r]);
    float s2 = (v[0][r] * v[0][r] + v[1][r] * v[1][r]) + (v[2][r] * v[2][r] + v[3][r] * v[3][r]);
#pragma unroll
    for (int off = 8; off; off >>= 1) {
      s1 += __shfl_xor(s1, off);
      s2 += __shfl_xor(s2, off);
    }
    if (rr == 0) {
      int lrow = wr * 16 + g4 + r;
      wsum[wid][lrow & 15][0] = s1;
      wsum[wid][lrow & 15][1] = s2;
    }
  }
  __syncthreads();
  if (tid < 32) {
    int row = tid;
    int band = row >> 4;
    float s1 = 0.f, s2 = 0.f;
#pragma unroll
    for (int k = 0; k < 4; ++k) {
      s1 += wsum[band * 4 + k][row & 15][0];
      s2 += wsum[band * 4 + k][row & 15][1];
    }
    float mu = s1 * (1.f / 256.f);
    float var = s2 * (1.f / 256.f) - mu * mu;
    stats[row][0] = mu;
    stats[row][1] = rsqrtf(var + 1e-5f);
  }
  __syncthreads();
#pragma unroll
  for (int r = 0; r < 4; ++r) {
    int lrow = wr * 16 + g4 + r;
    int grow = m0 + lrow;
    float mu = stats[lrow][0], rs = stats[lrow][1];
#pragma unroll
    for (int ni = 0; ni < 4; ++ni) {
      float y = (v[ni][r] - mu) * rs * scv[ni] + biv[ni];
      out32[(size_t)grow * 256 + col[ni]] = y;
      out16[(size_t)grow * 256 + col[ni]] = (bf16)y;
    }
  }
}

// --------------------------- Fully-fused pos-layer: Wo+LN1+FFN1+FFN2+LN2
// 64x256, 1024 thr, BK=64 phases (36 total, 8 MFMAs each), T4 counted vmcnt,
// generic chunk swizzle c^((c>>3)&7) (128B rows -> 8 chunks/row).
__global__ __launch_bounds__(1024, 4) void gemm_ln_ffn_kernel(
    const bf16* __restrict__ A, const bf16* __restrict__ Bt,
    const float* __restrict__ bias, const float* __restrict__ resid,
    const float* __restrict__ lns, const float* __restrict__ lnb,
    const bf16* __restrict__ W1t, const float* __restrict__ b1,
    const bf16* __restrict__ W2t, const float* __restrict__ b2,
    const float* __restrict__ ln2s, const float* __restrict__ ln2b,
    float* __restrict__ out32, bf16* __restrict__ out16) {
  __shared__ bf16 As[2 * 4096];        // 16 KB: 64 rows x 64 k per buffer
  __shared__ bf16 Bs[2 * 16384];       // 64 KB: 256 rows x 64 k per buffer
  __shared__ bf16 vL[64 * 264];        // 33 KB
  __shared__ bf16 hch[64 * 264];       // 33 KB
  __shared__ float wsum[16][16][2];
  __shared__ float stats[64][2];
  const int tid = threadIdx.x, lane = tid & 63, wid = tid >> 6;
  const int m0 = blockIdx.x * 64;
  const int wr = wid >> 2, wc = wid & 3;
  const int rr = lane & 15, g4 = (lane >> 4) * 4, g8 = (lane >> 4) * 8;
  const int g = lane >> 4;
  const char* Ab = (const char*)A;
  const char* Bb = (const char*)Bt;
  const size_t strideA = 512;    // A rows: K=256 bf16
  const size_t strideW1 = 512;   // W1t rows: K=256
  const size_t strideW2 = 2048;  // W2t rows: K=1024

  int col[4];
#pragma unroll
  for (int ni = 0; ni < 4; ++ni) col[ni] = wc * 64 + ni * 16 + rr;

  // A: 64 rows x 64 k per buffer (8 KB = 512 chunks) -> waves 0..7, 1 load.
  auto stageA = [&](int kk, int buf) {
    if (wid < 8) {
      int cp = wid * 64 + lane;               // phys chunk 0..511
      int cl = cp ^ ((cp >> 3) & 7);          // logical chunk (involution)
      int row = cl >> 3, gq = cl & 7;
      const char* a1 = Ab + (size_t)(m0 + row) * strideA + (size_t)kk * 2 + gq * 16;
      __builtin_amdgcn_global_load_lds((const AS1 u32*)a1,
                                       (AS3 u32*)((char*)As + buf * 8192 + cp * 16), 16, 0, 0);
    }
  };
  // B: 256 rows x 64 k per buffer (32 KB = 2048 chunks) -> 16 waves, 2 loads.
  auto stageB = [&](const char* Wb, size_t strideB, int rbase, int kk, int buf) {
#pragma unroll
    for (int j = 0; j < 2; ++j) {
      int cp = wid * 128 + j * 64 + lane;     // phys chunk 0..2047
      int cl = cp ^ ((cp >> 3) & 7);
      int row = cl >> 3, gq = cl & 7;
      const char* b1p = Wb + (size_t)(rbase + row) * strideB + (size_t)kk * 2 + gq * 16;
      __builtin_amdgcn_global_load_lds((const AS1 u32*)b1p,
                                       (AS3 u32*)((char*)Bs + buf * 32768 + cp * 16), 16, 0, 0);
    }
  };
  // swizzled fragment reads; nrow*8 + s*4 + g, cb>>3 == nrow (s*4+g < 8)
  auto breadB = [&](int buf, int nrow, int s) -> bf16x8 {
    int cb = nrow * 8 + s * 4 + g;
    int cs = cb ^ (nrow & 7);
    return *(const bf16x8*)&Bs[buf * 16384 + cs * 8];
  };
  auto areadA = [&](int buf, int nrow, int s) -> bf16x8 {
    int cb = nrow * 8 + s * 4 + g;
    int cs = cb ^ (nrow & 7);
    return *(const bf16x8*)&As[buf * 4096 + cs * 8];
  };

  // ---------------- phase 1: Wo GEMM (K=256, BK=64, T4 pipeline) -------------
  f32x4 acc[4] = {};
  stageA(0, 0);
  stageB(Bb, strideA, 0, 0, 0);
  {
    int cur = 0;
    for (int k0 = 0; k0 < 256; k0 += 64) {
      const bool pf = (k0 + 64 < 256);
      if (pf) {
        stageA(k0 + 64, cur ^ 1);
        stageB(Bb, strideA, 0, k0 + 64, cur ^ 1);
        if (wid < 8) asm volatile("s_waitcnt vmcnt(3)" ::: "memory");
        else         asm volatile("s_waitcnt vmcnt(2)" ::: "memory");
      } else {
        asm volatile("s_waitcnt vmcnt(0)" ::: "memory");
      }
      __builtin_amdgcn_s_barrier();
      __builtin_amdgcn_sched_barrier(0);
#pragma unroll
      for (int s = 0; s < 2; ++s) {
        bf16x8 af = areadA(cur, wr * 16 + rr, s);
        bf16x8 bfr[4];
#pragma unroll
        for (int ni = 0; ni < 4; ++ni)
          bfr[ni] = breadB(cur, wc * 64 + ni * 16 + rr, s);
#pragma unroll
        for (int ni = 0; ni < 4; ++ni)
          acc[ni] = __builtin_amdgcn_mfma_f32_16x16x32_bf16(af, bfr[ni], acc[ni], 0, 0, 0);
      }
      __builtin_amdgcn_sched_barrier(0);
      __builtin_amdgcn_s_barrier();
      cur ^= 1;
    }
  }

  // ---------------- LN1 -> y in regs + vL (bf16) ----------------
  float y[4][4];
  {
    float bv[4], scv[4], biv[4];
#pragma unroll
    for (int ni = 0; ni < 4; ++ni) {
      bv[ni] = bias[col[ni]];
      scv[ni] = lns[col[ni]];
      biv[ni] = lnb[col[ni]];
    }
    float v[4][4];
#pragma unroll
    for (int r = 0; r < 4; ++r) {
      int grow = m0 + wr * 16 + g4 + r;
#pragma unroll
      for (int ni = 0; ni < 4; ++ni)
        v[ni][r] = acc[ni][r] + bv[ni] + resid[(size_t)grow * 256 + col[ni]];
    }
#pragma unroll
    for (int r = 0; r < 4; ++r) {
      float s1 = (v[0][r] + v[1][r]) + (v[2][r] + v[3][r]);
      float s2 = (v[0][r] * v[0][r] + v[1][r] * v[1][r]) + (v[2][r] * v[2][r] + v[3][r] * v[3][r]);
#pragma unroll
      for (int off = 8; off; off >>= 1) {
        s1 += __shfl_xor(s1, off);
        s2 += __shfl_xor(s2, off);
      }
      if (rr == 0) {
        wsum[wid][g4 + r][0] = s1;
        wsum[wid][g4 + r][1] = s2;
      }
    }
    __syncthreads();
    if (tid < 64) {
      int row = tid;
      int band = row >> 4;
      float s1 = 0.f, s2 = 0.f;
#pragma unroll
      for (int k = 0; k < 4; ++k) {
        s1 += wsum[band * 4 + k][row & 15][0];
        s2 += wsum[band * 4 + k][row & 15][1];
      }
      float mu = s1 * (1.f / 256.f);
      float var = s2 * (1.f / 256.f) - mu * mu;
      stats[row][0] = mu;
      stats[row][1] = rsqrtf(var + 1e-5f);
    }
    __syncthreads();
#pragma unroll
    for (int r = 0; r < 4; ++r) {
      int lrow = wr * 16 + g4 + r;
      float mu = stats[lrow][0], rs = stats[lrow][1];
#pragma unroll
      for (int ni = 0; ni < 4; ++ni) {
        float yy = (v[ni][r] - mu) * rs * scv[ni] + biv[ni];
        y[ni][r] = yy;
        vL[lrow * 264 + col[ni]] = (bf16)yy;
      }
    }
  }
  __syncthreads();

  // ---------------- FFN1 chunk + FFN2 K-slice, nb = 0..3 (T4 pipelines) ------
  const char* W1b = (const char*)W1t;
  const char* W2b = (const char*)W2t;
  f32x4 acc2[4] = {};

  for (int nb = 0; nb < 4; ++nb) {
    // FFN1: hch = relu(vL @ W1[nb] + b1[nb]); K=256, BK=64
    f32x4 acc1[4] = {};
    stageB(W1b, strideW1, nb * 256, 0, 0);
    {
      int cur = 0;
      for (int k0 = 0; k0 < 256; k0 += 64) {
        const bool pf = (k0 + 64 < 256);
        if (pf) {
          stageB(W1b, strideW1, nb * 256, k0 + 64, cur ^ 1);
          asm volatile("s_waitcnt vmcnt(2)" ::: "memory");
        } else {
          asm volatile("s_waitcnt vmcnt(0)" ::: "memory");
        }
        __builtin_amdgcn_s_barrier();
        __builtin_amdgcn_sched_barrier(0);
#pragma unroll
        for (int s = 0; s < 2; ++s) {
          bf16x8 af = *(const bf16x8*)&vL[(wr * 16 + rr) * 264 + k0 + s * 32 + g8];
          bf16x8 bfr[4];
#pragma unroll
          for (int ni = 0; ni < 4; ++ni)
            bfr[ni] = breadB(cur, wc * 64 + ni * 16 + rr, s);
#pragma unroll
          for (int ni = 0; ni < 4; ++ni)
            acc1[ni] = __builtin_amdgcn_mfma_f32_16x16x32_bf16(af, bfr[ni], acc1[ni], 0, 0, 0);
        }
        __builtin_amdgcn_sched_barrier(0);
        __builtin_amdgcn_s_barrier();
        cur ^= 1;
      }
    }
#pragma unroll
    for (int ni = 0; ni < 4; ++ni) {
      float bb = b1[nb * 256 + col[ni]];
#pragma unroll
      for (int r = 0; r < 4; ++r) {
        int lrow = wr * 16 + g4 + r;
        hch[lrow * 264 + col[ni]] = (bf16)fmaxf(acc1[ni][r] + bb, 0.f);
      }
    }
    __syncthreads();

    // FFN2 partial: acc2 += hch @ W2[:, nb-slice]; K=256, BK=64
    stageB(W2b, strideW2, 0, nb * 256, 0);
    {
      int cur = 0;
      for (int k0 = 0; k0 < 256; k0 += 64) {
        const bool pf = (k0 + 64 < 256);
        if (pf) {
          stageB(W2b, strideW2, 0, nb * 256 + k0 + 64, cur ^ 1);
          asm volatile("s_waitcnt vmcnt(2)" ::: "memory");
        } else {
          asm volatile("s_waitcnt vmcnt(0)" ::: "memory");
        }
        __builtin_amdgcn_s_barrier();
        __builtin_amdgcn_sched_barrier(0);
#pragma unroll
        for (int s = 0; s < 2; ++s) {
          bf16x8 af = *(const bf16x8*)&hch[(wr * 16 + rr) * 264 + k0 + s * 32 + g8];
          bf16x8 bfr[4];
#pragma unroll
          for (int ni = 0; ni < 4; ++ni)
            bfr[ni] = breadB(cur, wc * 64 + ni * 16 + rr, s);
#pragma unroll
          for (int ni = 0; ni < 4; ++ni)
            acc2[ni] = __builtin_amdgcn_mfma_f32_16x16x32_bf16(af, bfr[ni], acc2[ni], 0, 0, 0);
        }
        __builtin_amdgcn_sched_barrier(0);
        __builtin_amdgcn_s_barrier();
        cur ^= 1;
      }
    }
    __syncthreads();   // hch will be overwritten next nb
  }

  // ---------------- LN2 over y + f ----------------
  {
    float bv[4], scv[4], biv[4];
#pragma unroll
    for (int ni = 0; ni < 4; ++ni) {
      bv[ni] = b2[col[ni]];
      scv[ni] = ln2s[col[ni]];
      biv[ni] = ln2b[col[ni]];
    }
    float v[4][4];
#pragma unroll
    for (int r = 0; r < 4; ++r)
#pragma unroll
      for (int ni = 0; ni < 4; ++ni)
        v[ni][r] = y[ni][r] + acc2[ni][r] + bv[ni];
#pragma unroll
    for (int r = 0; r < 4; ++r) {
      float s1 = (v[0][r] + v[1][r]) + (v[2][r] + v[3][r]);
      float s2 = (v[0][r] * v[0][r] + v[1][r] * v[1][r]) + (v[2][r] * v[2][r] + v[3][r] * v[3][r]);
#pragma unroll
      for (int off = 8; off; off >>= 1) {
        s1 += __shfl_xor(s1, off);
        s2 += __shfl_xor(s2, off);
      }
      if (rr == 0) {
        wsum[wid][g4 + r][0] = s1;
        wsum[wid][g4 + r][1] = s2;
      }
    }
    __syncthreads();
    if (tid < 64) {
      int row = tid;
      int band = row >> 4;
      float s1 = 0.f, s2 = 0.f;
#pragma unroll
      for (int k = 0; k < 4; ++k) {
        s1 += wsum[band * 4 + k][row & 15][0];
        s2 += wsum[band * 4 + k][row & 15][1];
      }
      float mu = s1 * (1.f / 256.f);
      float var = s2 * (1.f / 256.f) - mu * mu;
      stats[row][0] = mu;
      stats[row][1] = rsqrtf(var + 1e-5f);
    }
    __syncthreads();
#pragma unroll
    for (int r = 0; r < 4; ++r) {
      int lrow = wr * 16 + g4 + r;
      int grow = m0 + lrow;
      float mu = stats[lrow][0], rs = stats[lrow][1];
#pragma unroll
      for (int ni = 0; ni < 4; ++ni) {
        float yy = (v[ni][r] - mu) * rs * scv[ni] + biv[ni];
        out32[(size_t)grow * 256 + col[ni]] = yy;
        out16[(size_t)grow * 256 + col[ni]] = (bf16)yy;
      }
    }
  }
}

// ---------------------------------------------------------------- attention
static constexpr int LDV = 534;  // Vt row stride (bf16)
static constexpr float LOG2E = 1.4426950408889634f;
static constexpr float KSC = 0.17677669529663687f * LOG2E;  // scale * log2e

__device__ __forceinline__ int jloc(int r, int hi) { return (r & 3) + 8 * (r >> 2) + 4 * hi; }

__device__ __forceinline__ f32x16 qk_tile_g(const bf16* __restrict__ kbase, int jbase, int lq,
                                            const bf16x8& qf0, const bf16x8& qf1, int hi) {
  const bf16* kr = kbase + (size_t)(jbase + lq) * 256 + hi * 8;
  bf16x8 ka0 = *(const bf16x8*)(kr);
  bf16x8 ka1 = *(const bf16x8*)(kr + 16);
  f32x16 c = {};
  c = __builtin_amdgcn_mfma_f32_32x32x16_bf16(ka0, qf0, c, 0, 0, 0);
  c = __builtin_amdgcn_mfma_f32_32x32x16_bf16(ka1, qf1, c, 0, 0, 0);
  return c;
}

template <bool MASKED>
__device__ __forceinline__ void tileA(const f32x16& c, int jbase, int hi, int qlim, float& tot) {
  float t[4] = {0.f, 0.f, 0.f, 0.f};
#pragma unroll
  for (int q2 = 0; q2 < 4; ++q2)
#pragma unroll
    for (int p = 0; p < 4; ++p) {
      const int r = q2 * 4 + p;
      float e = __builtin_amdgcn_exp2f(c[r] * KSC);
      if (MASKED) {
        int j = jbase + 8 * q2 + 4 * hi + p;
        if (j > qlim) e = 0.f;
      }
      t[q2] += e;
    }
  tot += (t[0] + t[1]) + (t[2] + t[3]);
}

template <bool MASKED>
__device__ __forceinline__ void tileB(const f32x16& c, int jbase, int lq, int hi,
                                      int qlim, float itot, float gneg2, float posf,
                                      const bf16* Vt, float& run, float& sum2, f32x16& pvacc) {
  float su2[16], lcs[16], G[4];
#pragma unroll
  for (int q2 = 0; q2 < 4; ++q2) {
    float a = 0.f;
#pragma unroll
    for (int p = 0; p < 4; ++p) {
      const int r = q2 * 4 + p;
      su2[r] = c[r] * KSC;
      float e = __builtin_amdgcn_exp2f(su2[r]);
      if (MASKED) {
        int j = jbase + 8 * q2 + 4 * hi + p;
        if (j > qlim) e = 0.f;
      }
      a += e;
      lcs[r] = a;
    }
    G[q2] = a;
  }
  float Po[4];
#pragma unroll
  for (int q2 = 0; q2 < 4; ++q2) Po[q2] = __shfl_xor(G[q2], 32);
  float base[4];
  {
    float pre = run;
#pragma unroll
    for (int q2 = 0; q2 < 4; ++q2) {
      base[q2] = pre + (hi ? Po[q2] : 0.f);
      pre += G[q2] + Po[q2];
    }
    run = pre;
  }
#pragma unroll
  for (int cc = 0; cc < 2; ++cc) {
    float pv[8];
#pragma unroll
    for (int q2s = 0; q2s < 2; ++q2s) {
      const int q2 = cc * 2 + q2s;
#pragma unroll
      for (int p = 0; p < 4; ++p) {
        const int r = q2 * 4 + p;
        float cum = base[q2] + lcs[r];
        float pos = posf - (float)(8 * q2 + p);
        float d2 = fmaxf(__builtin_fmaf(-cum, itot, 1.f) * pos, 0.f);
        float dist = __builtin_amdgcn_sqrtf(d2);
        float eff = fmaxf(__builtin_amdgcn_exp2f(dist * gneg2), 1e-5f);
        float t = __builtin_amdgcn_exp2f(su2[r] * eff);
        if (MASKED) {
          int j = jbase + 8 * q2 + 4 * hi + p;
          if (j > qlim) t = 0.f;
        }
        pv[q2s * 4 + p] = t;
      }
    }
    sum2 += ((pv[0] + pv[1]) + (pv[2] + pv[3])) + ((pv[4] + pv[5]) + (pv[6] + pv[7]));
    u32 a0, a1, b0, b1;
    {
      bf16x2 t0 = {(bf16)pv[0], (bf16)pv[1]};
      bf16x2 t1 = {(bf16)pv[2], (bf16)pv[3]};
      bf16x2 t2 = {(bf16)pv[4], (bf16)pv[5]};
      bf16x2 t3 = {(bf16)pv[6], (bf16)pv[7]};
      a0 = __builtin_bit_cast(u32, t0);
      a1 = __builtin_bit_cast(u32, t1);
      b0 = __builtin_bit_cast(u32, t2);
      b1 = __builtin_bit_cast(u32, t3);
    }
    asm volatile("v_permlane32_swap_b32 %0, %1" : "+v"(a0), "+v"(b0));
    asm volatile("v_permlane32_swap_b32 %0, %1" : "+v"(a1), "+v"(b1));
    uint4 fq; fq.x = a0; fq.y = a1; fq.z = b0; fq.w = b1;
    bf16x8 pa = __builtin_bit_cast(bf16x8, fq);
    bf16x8 vb = *(const bf16x8*)&Vt[(size_t)lq * LDV + jbase + cc * 16 + hi * 8];
    pvacc = __builtin_amdgcn_mfma_f32_32x32x16_bf16(pa, vb, pvacc, 0, 0, 0);
  }
}

// Parity-split: block (bh, pi), 512 thr / 8 waves; wave p = wid&3,
// front = wid<4.  Pair: qbLo = pi+2p, qbHi = pi+14-2p, f = 7-2p.
// front: qbLo full + qbHi[0,f); back: qbHi[f, ntHi).  Both pi+8 tiles/pass.
// K and Q fragments read from global (L2-resident); V staged transposed.
// launch_bounds(512, 6): force VGPR <= 85 so 3 blocks/CU become resident.
__global__ __launch_bounds__(512, 6) void attn_kernel(
    const bf16* __restrict__ kh, const bf16* __restrict__ vh,
    const float* __restrict__ gam, bf16* __restrict__ o, int incl_diag) {
  __shared__ bf16 Vt[32 * LDV];      // 34176 B
  __shared__ float exA[4][32];
  __shared__ float exB[4][32];
  __shared__ float s2A[4][32];
  __shared__ float pvp[4][32][32];   // 16 KB

  const int tid = threadIdx.x;
  const int lane = tid & 63;
  const int wid = tid >> 6;          // 0..7
  const int bh = blockIdx.x;
  const int pi = blockIdx.y;         // parity 0/1
  const int b = bh >> 3, h = bh & 7;
  const bf16* kbase = kh + ((size_t)b * 4096 + h) * 32;
  const bf16* vbase = vh + ((size_t)b * 4096 + h) * 32;
  bf16* obase = o + ((size_t)b * 4096 + h) * 32;

  // stage V transposed: Vt[dk][j] (512 threads, 2 dk-chunks each)
  {
    int u = tid & 255;
#pragma unroll
    for (int cgi = 0; cgi < 2; ++cgi) {
      int cg = (tid >> 8) * 2 + cgi;   // 0..3
      const bf16* vb = vbase + (size_t)(2 * u) * 256 + cg * 8;
      bf16x8 r0 = *(const bf16x8*)(vb);
      bf16x8 r1 = *(const bf16x8*)(vb + 256);
#pragma unroll
      for (int e = 0; e < 8; ++e) {
        bf16x2 w2 = {r0[e], r1[e]};
        *(bf16x2*)&Vt[(size_t)(cg * 8 + e) * LDV + 2 * u] = w2;
      }
    }
  }
  __syncthreads();

  float gm = gam[h];
  float gneg = -(fmaxf(gm, 0.f) + log1pf(__expf(-fabsf(gm))));
  const float gneg2 = gneg * LOG2E;
  const int lq = lane & 31;
  const int hi = lane >> 5;

  const int p = wid & 3;
  const bool front = wid < 4;
  const int f = 7 - 2 * p;            // front's qbHi tile count
  const int qbLo = pi + 2 * p;
  const int qbHi = pi + 14 - 2 * p;
  const int ntHi = qbHi + 1;
  const int q0Hi = qbHi * 32;
  const int qrHi = q0Hi + lq;
  const int qlimHi = incl_diag ? qrHi : qrHi - 1;
  const int q0Lo = qbLo * 32;
  const int qrLo = q0Lo + lq;
  const int qlimLo = incl_diag ? qrLo : qrLo - 1;

  const bf16* qrowH = kbase + (size_t)(q0Hi + lq) * 256 + hi * 8;
  const bf16x8 qfH0 = *(const bf16x8*)(qrowH);
  const bf16x8 qfH1 = *(const bf16x8*)(qrowH + 16);

  // ---- pass A ----
  float totLo = 0.f, S = 0.f;
  if (front) {
    const bf16* qrowL = kbase + (size_t)(q0Lo + lq) * 256 + hi * 8;
    const bf16x8 qfL0 = *(const bf16x8*)(qrowL);
    const bf16x8 qfL1 = *(const bf16x8*)(qrowL + 16);
    for (int jt = 0; jt < qbLo; ++jt) {
      f32x16 c = qk_tile_g(kbase, jt * 32, lq, qfL0, qfL1, hi);
      tileA<false>(c, jt * 32, hi, qlimLo, totLo);
    }
    {
      f32x16 c = qk_tile_g(kbase, q0Lo, lq, qfL0, qfL1, hi);
      tileA<true>(c, q0Lo, hi, qlimLo, totLo);
    }
    totLo += __shfl_xor(totLo, 32);
    for (int jt = 0; jt < f; ++jt) {
      f32x16 c = qk_tile_g(kbase, jt * 32, lq, qfH0, qfH1, hi);
      tileA<false>(c, jt * 32, hi, qlimHi, S);
    }
    S += __shfl_xor(S, 32);
    if (lane < 32) exA[p][lq] = S;
  } else {
    for (int jt = f; jt < ntHi - 1; ++jt) {
      f32x16 c = qk_tile_g(kbase, jt * 32, lq, qfH0, qfH1, hi);
      tileA<false>(c, jt * 32, hi, qlimHi, S);
    }
    {
      f32x16 c = qk_tile_g(kbase, q0Hi, lq, qfH0, qfH1, hi);
      tileA<true>(c, q0Hi, hi, qlimHi, S);
    }
    S += __shfl_xor(S, 32);
    if (lane < 32) exB[p][lq] = S;
  }
  __syncthreads();
  const float SA = exA[p][lq];
  const float SB = exB[p][lq];
  const float totHi = SA + SB;
  const float itotHi = totHi > 0.f ? 1.f / totHi : 0.f;

  // ---- pass B ----
  f32x16 pvHi = {};
  float sum2Hi = 0.f;
  if (front) {
    const bf16* qrowL = kbase + (size_t)(q0Lo + lq) * 256 + hi * 8;
    const bf16x8 qfL0 = *(const bf16x8*)(qrowL);
    const bf16x8 qfL1 = *(const bf16x8*)(qrowL + 16);
    const float itotLo = totLo > 0.f ? 1.f / totLo : 0.f;
    f32x16 pvLo = {};
    float sum2Lo = 0.f, run = 0.f;
    float posf = (float)(qrLo - 4 * hi);
    for (int jt = 0; jt < qbLo; ++jt) {
      f32x16 c = qk_tile_g(kbase, jt * 32, lq, qfL0, qfL1, hi);
      tileB<false>(c, jt * 32, lq, hi, qlimLo, itotLo, gneg2, posf, Vt, run, sum2Lo, pvLo);
      posf -= 32.f;
    }
    {
      f32x16 c = qk_tile_g(kbase, q0Lo, lq, qfL0, qfL1, hi);
      tileB<true>(c, q0Lo, lq, hi, qlimLo, itotLo, gneg2, posf, Vt, run, sum2Lo, pvLo);
    }
    sum2Lo += __shfl_xor(sum2Lo, 32);
    const float inv2Lo = sum2Lo > 0.f ? 1.f / sum2Lo : 0.f;
#pragma unroll
    for (int r = 0; r < 16; ++r) {
      int qv = jloc(r, hi);
      float iv = __shfl(inv2Lo, qv);
      obase[(size_t)(q0Lo + qv) * 256 + lq] = (bf16)(pvLo[r] * iv);
    }
    run = 0.f;
    posf = (float)(qrHi - 4 * hi);
    for (int jt = 0; jt < f; ++jt) {
      f32x16 c = qk_tile_g(kbase, jt * 32, lq, qfH0, qfH1, hi);
      tileB<false>(c, jt * 32, lq, hi, qlimHi, itotHi, gneg2, posf, Vt, run, sum2Hi, pvHi);
      posf -= 32.f;
    }
    sum2Hi += __shfl_xor(sum2Hi, 32);
    if (lane < 32) s2A[p][lq] = sum2Hi;
#pragma unroll
    for (int r = 0; r < 16; ++r) pvp[p][jloc(r, hi)][lq] = pvHi[r];
  } else {
    float run = SA;
    float posf = (float)(qrHi - 4 * hi - 32 * f);
    for (int jt = f; jt < ntHi - 1; ++jt) {
      f32x16 c = qk_tile_g(kbase, jt * 32, lq, qfH0, qfH1, hi);
      tileB<false>(c, jt * 32, lq, hi, qlimHi, itotHi, gneg2, posf, Vt, run, sum2Hi, pvHi);
      posf -= 32.f;
    }
    {
      f32x16 c = qk_tile_g(kbase, q0Hi, lq, qfH0, qfH1, hi);
      tileB<true>(c, q0Hi, lq, hi, qlimHi, itotHi, gneg2, posf, Vt, run, sum2Hi, pvHi);
    }
    sum2Hi += __shfl_xor(sum2Hi, 32);
  }
  __syncthreads();
  if (!front) {
    const float s2 = s2A[p][lq] + sum2Hi;
    const float inv2 = s2 > 0.f ? 1.f / s2 : 0.f;
#pragma unroll
    for (int r = 0; r < 16; ++r) {
      int qv = jloc(r, hi);
      float iv = __shfl(inv2, qv);
      float val = pvHi[r] + pvp[p][qv][lq];
      obase[(size_t)(q0Hi + qv) * 256 + lq] = (bf16)(val * iv);
    }
  }
}

// ---------------------------------------------------------------- host
extern "C" void kernel_launch(void* const* d_in, const int* in_sizes, int n_in,
                              void* d_out, int out_size, void* d_ws, size_t ws_size,
                              hipStream_t stream) {
  const float* q_embed  = (const float*)d_in[0];
  const float* qa_embed = (const float*)d_in[1];
  const float* Wk = (const float*)d_in[2];
  const float* bk = (const float*)d_in[3];
  const float* Wv = (const float*)d_in[4];
  const float* bv = (const float*)d_in[5];
  const float* Wo = (const float*)d_in[6];
  const float* bo = (const float*)d_in[7];
  const float* gammas = (const float*)d_in[8];
  const float* ln1_s = (const float*)d_in[9];
  const float* ln1_b = (const float*)d_in[10];
  const float* W1 = (const float*)d_in[11];
  const float* b1 = (const float*)d_in[12];
  const float* W2 = (const float*)d_in[13];
  const float* b2 = (const float*)d_in[14];
  const float* ln2_s = (const float*)d_in[15];
  const float* ln2_b = (const float*)d_in[16];
  float* out = (float*)d_out;

  char* ws = (char*)d_ws;
  float* y32 = (float*)(ws);
  float* x32 = (float*)(ws + ((size_t)16 << 20));
  bf16* y16  = (bf16*)(ws + ((size_t)32 << 20));
  bf16* x16  = (bf16*)(ws + ((size_t)40 << 20));
  bf16* khb  = (bf16*)(ws + ((size_t)48 << 20));
  bf16* vhb  = (bf16*)(ws + ((size_t)56 << 20));
  bf16* o16  = (bf16*)(ws + ((size_t)64 << 20));
  bf16* Wkt  = (bf16*)(ws + ((size_t)122 << 20));
  bf16* Wvt  = Wkt + 6 * 65536;
  bf16* Wot  = Wvt + 6 * 65536;
  bf16* W1t  = Wot + 6 * 65536;      // [N=1024][K=256] per layer
  bf16* W2t  = W1t + 6 * 262144;     // [N=256][K=1024] per layer

  transpose_cvt_all<<<dim3(16, 16, 30), 256, 0, stream>>>(Wk, Wv, Wo, W1, W2,
                                                          Wkt, Wvt, Wot, W1t, W2t);
  cvt_copy2_kernel<<<dim3(4096, 2), 256, 0, stream>>>(q_embed, x32, x16,
                                                      qa_embed, y32, y16, Mc * 256 / 4);

  for (int i = 0; i < 6; ++i) {
    const bool first = (i < 2);
    const bool strict = (i == 3 || i == 5);   // mask_flag==0 layers
    const bool pos = first || strict;         // apply_pos
    bf16* in16 = first ? y16 : x16;           // q/k input (kq_same)
    bf16* v16  = (first || strict) ? y16 : x16;
    float* res32 = first ? y32 : x32;

    gemm_kv_kernel<<<dim3(128, 4), 256, 0, stream>>>(
        in16, Wkt + (size_t)i * 65536, bk + i * 256, khb,
        v16, Wvt + (size_t)i * 65536, bv + i * 256, vhb, 256, 256);
    attn_kernel<<<dim3(256, 2), 512, 0, stream>>>(khb, vhb, gammas + i * 8, o16, strict ? 0 : 1);
    if (pos) {
      float* fin = (i == 5) ? out : res32;
      gemm_ln_ffn_kernel<<<256, 1024, 0, stream>>>(
          o16, Wot + (size_t)i * 65536, bo + i * 256, res32,
          ln1_s + i * 256, ln1_b + i * 256,
          W1t + (size_t)i * 262144, b1 + i * 1024,
          W2t + (size_t)i * 262144, b2 + i * 256,
          ln2_s + i * 256, ln2_b + i * 256, fin, in16);
    } else {
      gemm_ln_kernel<256><<<512, 512, 0, stream>>>(
          o16, Wot + (size_t)i * 65536, bo + i * 256, res32,
          ln1_s + i * 256, ln1_b + i * 256, res32, in16);
    }
  }
}

// Round 20
// 518.743 us; speedup vs baseline: 1.0336x; 1.0336x over previous
//
#include <hip/hip_runtime.h>
#include <cstdint>
#include <cstddef>

// ---------------------------------------------------------------------------
// AKT-style 6-layer transformer forward on MI355X (gfx950).  Round 20 (FINAL):
//  - exact revert to R18 (best measured: 519.1 us).  R19's launch_bounds
//    squeeze spilled (WRITE 8->28 MB) and regressed; attention is at its
//    latency-structural plateau at 2 blocks/CU.
//  - attention: parity-split grid (256,2), V in LDS, K/Q from L2.
//  - pos layers: fully-fused Wo+LN1+FFN1+FFN2+LN2, BK=64 T4 pipeline,
//    chunk-swizzled LDS.  Non-pos: gemm_ln.  KV proj: BK=64 dbuf GEMM.
// ---------------------------------------------------------------------------

#define AS1 __attribute__((address_space(1)))
#define AS3 __attribute__((address_space(3)))

typedef __bf16 bf16;
typedef __bf16 bf16x8 __attribute__((ext_vector_type(8)));
typedef __bf16 bf16x4 __attribute__((ext_vector_type(4)));
typedef __bf16 bf16x2 __attribute__((ext_vector_type(2)));
typedef float  f32x4  __attribute__((ext_vector_type(4)));
typedef float  f32x16 __attribute__((ext_vector_type(16)));
typedef unsigned int u32;

static constexpr int Mc = 32 * 512; // 16384 rows

// ---------------------------------------------------------------- converts
__global__ void cvt_copy2_kernel(const float* __restrict__ s0, float* __restrict__ da32,
                                 bf16* __restrict__ da16, const float* __restrict__ s1,
                                 float* __restrict__ db32, bf16* __restrict__ db16, int n4) {
  const float* s = blockIdx.y ? s1 : s0;
  float* d32 = blockIdx.y ? db32 : da32;
  bf16* d16 = blockIdx.y ? db16 : da16;
  int i = blockIdx.x * blockDim.x + threadIdx.x;
  if (i < n4) {
    float4 v = ((const float4*)s)[i];
    ((float4*)d32)[i] = v;
    bf16x4 hx = {(bf16)v.x, (bf16)v.y, (bf16)v.z, (bf16)v.w};
    ((bf16x4*)d16)[i] = hx;
  }
}

// Tiled transpose+cvt for all 5 weights: W[K,N] fp32 -> Wt[N,K] bf16.
__global__ __launch_bounds__(256) void transpose_cvt_all(
    const float* __restrict__ Wk, const float* __restrict__ Wv, const float* __restrict__ Wo,
    const float* __restrict__ W1, const float* __restrict__ W2,
    bf16* __restrict__ Wkt, bf16* __restrict__ Wvt, bf16* __restrict__ Wot,
    bf16* __restrict__ W1t, bf16* __restrict__ W2t) {
  int z = blockIdx.z;
  int layer = z % 6, w = z / 6;
  const float* src; bf16* dst; int K, N;
  switch (w) {
    case 0: src = Wk; dst = Wkt; K = 256; N = 256; break;
    case 1: src = Wv; dst = Wvt; K = 256; N = 256; break;
    case 2: src = Wo; dst = Wot; K = 256; N = 256; break;
    case 3: src = W1; dst = W1t; K = 256; N = 1024; break;
    default: src = W2; dst = W2t; K = 1024; N = 256; break;
  }
  int k0 = blockIdx.x * 64, n0 = blockIdx.y * 64;
  if (k0 >= K || n0 >= N) return;
  src += (size_t)layer * K * N;
  dst += (size_t)layer * K * N;
  __shared__ bf16 t[64][68];
  int tid = threadIdx.x;
  int rr = tid >> 4;
  int c4 = (tid & 15) * 4;
#pragma unroll
  for (int p = 0; p < 4; ++p) {
    int k = rr + p * 16;
    float4 v = *(const float4*)(src + (size_t)(k0 + k) * N + n0 + c4);
    t[c4 + 0][k] = (bf16)v.x;
    t[c4 + 1][k] = (bf16)v.y;
    t[c4 + 2][k] = (bf16)v.z;
    t[c4 + 3][k] = (bf16)v.w;
  }
  __syncthreads();
#pragma unroll
  for (int p = 0; p < 4; ++p) {
    int nl = rr + p * 16;
    bf16x4 o4 = *(const bf16x4*)&t[nl][c4];
    *(bf16x4*)(dst + (size_t)(n0 + nl) * K + k0 + c4) = o4;
  }
}

// ---------------------------------------------------------------- GEMM (plain)
template <int RELU, typename OUT_T>
__device__ __forceinline__ void gemm_body(
    const bf16* __restrict__ A, const bf16* __restrict__ Bt,
    const float* __restrict__ bias, OUT_T* __restrict__ C,
    int K, int N, int m0, int n0, bf16* As, bf16* Bs) {
  const int tid = threadIdx.x;
  const int lane = tid & 63;
  const int wid = tid >> 6;
  const int wm = (wid >> 1) * 64;
  const int wn = (wid & 1) * 64;
  f32x4 acc[4][4] = {};

  const int o1 = wid * 1024 + lane * 16;
  const int o2 = o1 + 4096;
  const int r1 = o1 >> 6, c1 = o1 & 63;
  const int r2 = o2 >> 6, c2 = o2 & 63;
  const char* Ab = (const char*)A;
  const char* Bb = (const char*)Bt;
  const size_t stride = (size_t)K * 2;

  auto stage_panel = [&](int panel, int kk) {
    const char* a1 = Ab + (size_t)(m0 + r1) * stride + (size_t)kk * 2 + c1;
    const char* a2 = Ab + (size_t)(m0 + r2) * stride + (size_t)kk * 2 + c2;
    const char* b1 = Bb + (size_t)(n0 + r1) * stride + (size_t)kk * 2 + c1;
    const char* b2 = Bb + (size_t)(n0 + r2) * stride + (size_t)kk * 2 + c2;
    char* ad = (char*)As + panel * 8192 + wid * 1024;
    char* bd = (char*)Bs + panel * 8192 + wid * 1024;
    __builtin_amdgcn_global_load_lds((const AS1 u32*)a1, (AS3 u32*)ad, 16, 0, 0);
    __builtin_amdgcn_global_load_lds((const AS1 u32*)a2, (AS3 u32*)(ad + 4096), 16, 0, 0);
    __builtin_amdgcn_global_load_lds((const AS1 u32*)b1, (AS3 u32*)bd, 16, 0, 0);
    __builtin_amdgcn_global_load_lds((const AS1 u32*)b2, (AS3 u32*)(bd + 4096), 16, 0, 0);
  };

  stage_panel(0, 0);
  stage_panel(1, 32);
  asm volatile("s_waitcnt vmcnt(0)" ::: "memory");
  __syncthreads();

  int cur = 0;
  for (int k0 = 0; k0 < K; k0 += 64) {
    if (k0 + 64 < K) {
      stage_panel((cur ^ 1) * 2, k0 + 64);
      stage_panel((cur ^ 1) * 2 + 1, k0 + 96);
    }
    const int rr = lane & 15;
    const int g8 = (lane >> 4) * 8;
#pragma unroll
    for (int s = 0; s < 2; ++s) {
      const int base = (cur * 2 + s) * 4096;
      bf16x8 af[4], bfr[4];
#pragma unroll
      for (int i = 0; i < 4; ++i) {
        af[i]  = *(const bf16x8*)&As[base + (wm + i * 16 + rr) * 32 + g8];
        bfr[i] = *(const bf16x8*)&Bs[base + (wn + i * 16 + rr) * 32 + g8];
      }
#pragma unroll
      for (int mi = 0; mi < 4; ++mi)
#pragma unroll
        for (int ni = 0; ni < 4; ++ni)
          acc[mi][ni] = __builtin_amdgcn_mfma_f32_16x16x32_bf16(af[mi], bfr[ni], acc[mi][ni], 0, 0, 0);
    }
    asm volatile("s_waitcnt vmcnt(0)" ::: "memory");
    __syncthreads();
    cur ^= 1;
  }

  const int rr = lane & 15;
  const int g4 = (lane >> 4) * 4;
  float bv[4];
#pragma unroll
  for (int ni = 0; ni < 4; ++ni) bv[ni] = bias[n0 + wn + ni * 16 + rr];
#pragma unroll
  for (int mi = 0; mi < 4; ++mi)
#pragma unroll
    for (int ni = 0; ni < 4; ++ni)
#pragma unroll
      for (int r = 0; r < 4; ++r) {
        float v = acc[mi][ni][r] + bv[ni];
        if (RELU) v = fmaxf(v, 0.f);
        int row = m0 + wm + mi * 16 + g4 + r;
        int col = n0 + wn + ni * 16 + rr;
        C[(size_t)row * N + col] = (OUT_T)v;
      }
}

__global__ __launch_bounds__(256) void gemm_kv_kernel(
    const bf16* __restrict__ A0, const bf16* __restrict__ Bt0,
    const float* __restrict__ b0, bf16* __restrict__ C0,
    const bf16* __restrict__ A1, const bf16* __restrict__ Bt1,
    const float* __restrict__ b1, bf16* __restrict__ C1, int K, int N) {
  __shared__ bf16 As[4 * 4096];
  __shared__ bf16 Bs[4 * 4096];
  int sel = blockIdx.y >> 1;
  gemm_body<0, bf16>(sel ? A1 : A0, sel ? Bt1 : Bt0, sel ? b1 : b0, sel ? C1 : C0,
                     K, N, blockIdx.x * 128, (blockIdx.y & 1) * 128, As, Bs);
}

// ---------------------------------------------------------------- GEMM + LN (R9 32-row)
template <int KSZ>
__global__ __launch_bounds__(512, 4) void gemm_ln_kernel(
    const bf16* __restrict__ A, const bf16* __restrict__ Bt,
    const float* __restrict__ bias, const float* __restrict__ resid,
    const float* __restrict__ lns, const float* __restrict__ lnb,
    float* __restrict__ out32, bf16* __restrict__ out16) {
  __shared__ bf16 As[2 * 32 * 32];
  __shared__ bf16 Bs[2 * 256 * 32];
  __shared__ float wsum[8][16][2];
  __shared__ float stats[32][2];
  const int tid = threadIdx.x, lane = tid & 63, wid = tid >> 6;
  const int m0 = blockIdx.x * 32;
  const int wr = wid >> 2, wc = wid & 3;
  f32x4 acc[4] = {};
  const char* Ab = (const char*)A;
  const char* Bb = (const char*)Bt;
  const size_t stride = (size_t)KSZ * 2;

  auto stage = [&](int buf, int kk) {
    if (wid < 2) {
      int off = wid * 1024 + lane * 16;
      const char* a1 = Ab + (size_t)(m0 + (off >> 6)) * stride + (size_t)kk * 2 + (off & 63);
      __builtin_amdgcn_global_load_lds((const AS1 u32*)a1,
                                       (AS3 u32*)((char*)As + buf * 2048 + wid * 1024), 16, 0, 0);
    }
    int off1 = wid * 2048 + lane * 16;
    int off2 = off1 + 1024;
    const char* b1 = Bb + (size_t)(off1 >> 6) * stride + (size_t)kk * 2 + (off1 & 63);
    const char* b2 = Bb + (size_t)(off2 >> 6) * stride + (size_t)kk * 2 + (off2 & 63);
    char* bd = (char*)Bs + buf * 16384 + wid * 2048;
    __builtin_amdgcn_global_load_lds((const AS1 u32*)b1, (AS3 u32*)bd, 16, 0, 0);
    __builtin_amdgcn_global_load_lds((const AS1 u32*)b2, (AS3 u32*)(bd + 1024), 16, 0, 0);
  };

  stage(0, 0);
  asm volatile("s_waitcnt vmcnt(0)" ::: "memory");
  __syncthreads();

  int cur = 0;
  for (int k0 = 0; k0 < KSZ; k0 += 32) {
    if (k0 + 32 < KSZ) stage(cur ^ 1, k0 + 32);
    const int rr = lane & 15, g8 = (lane >> 4) * 8;
    bf16x8 af = *(const bf16x8*)&As[cur * 1024 + (wr * 16 + rr) * 32 + g8];
    bf16x8 bfr[4];
#pragma unroll
    for (int ni = 0; ni < 4; ++ni)
      bfr[ni] = *(const bf16x8*)&Bs[cur * 8192 + (wc * 64 + ni * 16 + rr) * 32 + g8];
#pragma unroll
    for (int ni = 0; ni < 4; ++ni)
      acc[ni] = __builtin_amdgcn_mfma_f32_16x16x32_bf16(af, bfr[ni], acc[ni], 0, 0, 0);
    asm volatile("s_waitcnt vmcnt(0)" ::: "memory");
    __syncthreads();
    cur ^= 1;
  }

  const int rr = lane & 15, g4 = (lane >> 4) * 4;
  float bv[4], scv[4], biv[4];
  int col[4];
#pragma unroll
  for (int ni = 0; ni < 4; ++ni) {
    col[ni] = wc * 64 + ni * 16 + rr;
    bv[ni] = bias[col[ni]];
    scv[ni] = lns[col[ni]];
    biv[ni] = lnb[col[ni]];
  }
  float v[4][4];
#pragma unroll
  for (int r = 0; r < 4; ++r) {
    int grow = m0 + wr * 16 + g4 + r;
#pragma unroll
    for (int ni = 0; ni < 4; ++ni)
      v[ni][r] = acc[ni][r] + bv[ni] + resid[(size_t)grow * 256 + col[ni]];
  }
#pragma unroll
  for (int r = 0; r < 4; ++r) {
    float s1 = (v[0][r] + v[1][r]) + (v[2][r] + v[3][r]);
    float s2 = (v[0][r] * v[0][r] + v[1][r] * v[1][r]) + (v[2][r] * v[2][r] + v[3][r] * v[3][r]);
#pragma unroll
    for (int off = 8; off; off >>= 1) {
      s1 += __shfl_xor(s1, off);
      s2 += __shfl_xor(s2, off);
    }
    if (rr == 0) {
      int lrow = wr * 16 + g4 + r;
      wsum[wid][lrow & 15][0] = s1;
      wsum[wid][lrow & 15][1] = s2;
    }
  }
  __syncthreads();
  if (tid < 32) {
    int row = tid;
    int band = row >> 4;
    float s1 = 0.f, s2 = 0.f;
#pragma unroll
    for (int k = 0; k < 4; ++k) {
      s1 += wsum[band * 4 + k][row & 15][0];
      s2 += wsum[band * 4 + k][row & 15][1];
    }
    float mu = s1 * (1.f / 256.f);
    float var = s2 * (1.f / 256.f) - mu * mu;
    stats[row][0] = mu;
    stats[row][1] = rsqrtf(var + 1e-5f);
  }
  __syncthreads();
#pragma unroll
  for (int r = 0; r < 4; ++r) {
    int lrow = wr * 16 + g4 + r;
    int grow = m0 + lrow;
    float mu = stats[lrow][0], rs = stats[lrow][1];
#pragma unroll
    for (int ni = 0; ni < 4; ++ni) {
      float y = (v[ni][r] - mu) * rs * scv[ni] + biv[ni];
      out32[(size_t)grow * 256 + col[ni]] = y;
      out16[(size_t)grow * 256 + col[ni]] = (bf16)y;
    }
  }
}

// --------------------------- Fully-fused pos-layer: Wo+LN1+FFN1+FFN2+LN2
// 64x256, 1024 thr, BK=64 phases (36 total, 8 MFMAs each), T4 counted vmcnt,
// generic chunk swizzle c^((c>>3)&7) (128B rows -> 8 chunks/row).
__global__ __launch_bounds__(1024, 4) void gemm_ln_ffn_kernel(
    const bf16* __restrict__ A, const bf16* __restrict__ Bt,
    const float* __restrict__ bias, const float* __restrict__ resid,
    const float* __restrict__ lns, const float* __restrict__ lnb,
    const bf16* __restrict__ W1t, const float* __restrict__ b1,
    const bf16* __restrict__ W2t, const float* __restrict__ b2,
    const float* __restrict__ ln2s, const float* __restrict__ ln2b,
    float* __restrict__ out32, bf16* __restrict__ out16) {
  __shared__ bf16 As[2 * 4096];        // 16 KB: 64 rows x 64 k per buffer
  __shared__ bf16 Bs[2 * 16384];       // 64 KB: 256 rows x 64 k per buffer
  __shared__ bf16 vL[64 * 264];        // 33 KB
  __shared__ bf16 hch[64 * 264];       // 33 KB
  __shared__ float wsum[16][16][2];
  __shared__ float stats[64][2];
  const int tid = threadIdx.x, lane = tid & 63, wid = tid >> 6;
  const int m0 = blockIdx.x * 64;
  const int wr = wid >> 2, wc = wid & 3;
  const int rr = lane & 15, g4 = (lane >> 4) * 4, g8 = (lane >> 4) * 8;
  const int g = lane >> 4;
  const char* Ab = (const char*)A;
  const char* Bb = (const char*)Bt;
  const size_t strideA = 512;    // A rows: K=256 bf16
  const size_t strideW1 = 512;   // W1t rows: K=256
  const size_t strideW2 = 2048;  // W2t rows: K=1024

  int col[4];
#pragma unroll
  for (int ni = 0; ni < 4; ++ni) col[ni] = wc * 64 + ni * 16 + rr;

  // A: 64 rows x 64 k per buffer (8 KB = 512 chunks) -> waves 0..7, 1 load.
  auto stageA = [&](int kk, int buf) {
    if (wid < 8) {
      int cp = wid * 64 + lane;               // phys chunk 0..511
      int cl = cp ^ ((cp >> 3) & 7);          // logical chunk (involution)
      int row = cl >> 3, gq = cl & 7;
      const char* a1 = Ab + (size_t)(m0 + row) * strideA + (size_t)kk * 2 + gq * 16;
      __builtin_amdgcn_global_load_lds((const AS1 u32*)a1,
                                       (AS3 u32*)((char*)As + buf * 8192 + cp * 16), 16, 0, 0);
    }
  };
  // B: 256 rows x 64 k per buffer (32 KB = 2048 chunks) -> 16 waves, 2 loads.
  auto stageB = [&](const char* Wb, size_t strideB, int rbase, int kk, int buf) {
#pragma unroll
    for (int j = 0; j < 2; ++j) {
      int cp = wid * 128 + j * 64 + lane;     // phys chunk 0..2047
      int cl = cp ^ ((cp >> 3) & 7);
      int row = cl >> 3, gq = cl & 7;
      const char* b1p = Wb + (size_t)(rbase + row) * strideB + (size_t)kk * 2 + gq * 16;
      __builtin_amdgcn_global_load_lds((const AS1 u32*)b1p,
                                       (AS3 u32*)((char*)Bs + buf * 32768 + cp * 16), 16, 0, 0);
    }
  };
  // swizzled fragment reads; nrow*8 + s*4 + g, cb>>3 == nrow (s*4+g < 8)
  auto breadB = [&](int buf, int nrow, int s) -> bf16x8 {
    int cb = nrow * 8 + s * 4 + g;
    int cs = cb ^ (nrow & 7);
    return *(const bf16x8*)&Bs[buf * 16384 + cs * 8];
  };
  auto areadA = [&](int buf, int nrow, int s) -> bf16x8 {
    int cb = nrow * 8 + s * 4 + g;
    int cs = cb ^ (nrow & 7);
    return *(const bf16x8*)&As[buf * 4096 + cs * 8];
  };

  // ---------------- phase 1: Wo GEMM (K=256, BK=64, T4 pipeline) -------------
  f32x4 acc[4] = {};
  stageA(0, 0);
  stageB(Bb, strideA, 0, 0, 0);
  {
    int cur = 0;
    for (int k0 = 0; k0 < 256; k0 += 64) {
      const bool pf = (k0 + 64 < 256);
      if (pf) {
        stageA(k0 + 64, cur ^ 1);
        stageB(Bb, strideA, 0, k0 + 64, cur ^ 1);
        if (wid < 8) asm volatile("s_waitcnt vmcnt(3)" ::: "memory");
        else         asm volatile("s_waitcnt vmcnt(2)" ::: "memory");
      } else {
        asm volatile("s_waitcnt vmcnt(0)" ::: "memory");
      }
      __builtin_amdgcn_s_barrier();
      __builtin_amdgcn_sched_barrier(0);
#pragma unroll
      for (int s = 0; s < 2; ++s) {
        bf16x8 af = areadA(cur, wr * 16 + rr, s);
        bf16x8 bfr[4];
#pragma unroll
        for (int ni = 0; ni < 4; ++ni)
          bfr[ni] = breadB(cur, wc * 64 + ni * 16 + rr, s);
#pragma unroll
        for (int ni = 0; ni < 4; ++ni)
          acc[ni] = __builtin_amdgcn_mfma_f32_16x16x32_bf16(af, bfr[ni], acc[ni], 0, 0, 0);
      }
      __builtin_amdgcn_sched_barrier(0);
      __builtin_amdgcn_s_barrier();
      cur ^= 1;
    }
  }

  // ---------------- LN1 -> y in regs + vL (bf16) ----------------
  float y[4][4];
  {
    float bv[4], scv[4], biv[4];
#pragma unroll
    for (int ni = 0; ni < 4; ++ni) {
      bv[ni] = bias[col[ni]];
      scv[ni] = lns[col[ni]];
      biv[ni] = lnb[col[ni]];
    }
    float v[4][4];
#pragma unroll
    for (int r = 0; r < 4; ++r) {
      int grow = m0 + wr * 16 + g4 + r;
#pragma unroll
      for (int ni = 0; ni < 4; ++ni)
        v[ni][r] = acc[ni][r] + bv[ni] + resid[(size_t)grow * 256 + col[ni]];
    }
#pragma unroll
    for (int r = 0; r < 4; ++r) {
      float s1 = (v[0][r] + v[1][r]) + (v[2][r] + v[3][r]);
      float s2 = (v[0][r] * v[0][r] + v[1][r] * v[1][r]) + (v[2][r] * v[2][r] + v[3][r] * v[3][r]);
#pragma unroll
      for (int off = 8; off; off >>= 1) {
        s1 += __shfl_xor(s1, off);
        s2 += __shfl_xor(s2, off);
      }
      if (rr == 0) {
        wsum[wid][g4 + r][0] = s1;
        wsum[wid][g4 + r][1] = s2;
      }
    }
    __syncthreads();
    if (tid < 64) {
      int row = tid;
      int band = row >> 4;
      float s1 = 0.f, s2 = 0.f;
#pragma unroll
      for (int k = 0; k < 4; ++k) {
        s1 += wsum[band * 4 + k][row & 15][0];
        s2 += wsum[band * 4 + k][row & 15][1];
      }
      float mu = s1 * (1.f / 256.f);
      float var = s2 * (1.f / 256.f) - mu * mu;
      stats[row][0] = mu;
      stats[row][1] = rsqrtf(var + 1e-5f);
    }
    __syncthreads();
#pragma unroll
    for (int r = 0; r < 4; ++r) {
      int lrow = wr * 16 + g4 + r;
      float mu = stats[lrow][0], rs = stats[lrow][1];
#pragma unroll
      for (int ni = 0; ni < 4; ++ni) {
        float yy = (v[ni][r] - mu) * rs * scv[ni] + biv[ni];
        y[ni][r] = yy;
        vL[lrow * 264 + col[ni]] = (bf16)yy;
      }
    }
  }
  __syncthreads();

  // ---------------- FFN1 chunk + FFN2 K-slice, nb = 0..3 (T4 pipelines) ------
  const char* W1b = (const char*)W1t;
  const char* W2b = (const char*)W2t;
  f32x4 acc2[4] = {};

  for (int nb = 0; nb < 4; ++nb) {
    // FFN1: hch = relu(vL @ W1[nb] + b1[nb]); K=256, BK=64
    f32x4 acc1[4] = {};
    stageB(W1b, strideW1, nb * 256, 0, 0);
    {
      int cur = 0;
      for (int k0 = 0; k0 < 256; k0 += 64) {
        const bool pf = (k0 + 64 < 256);
        if (pf) {
          stageB(W1b, strideW1, nb * 256, k0 + 64, cur ^ 1);
          asm volatile("s_waitcnt vmcnt(2)" ::: "memory");
        } else {
          asm volatile("s_waitcnt vmcnt(0)" ::: "memory");
        }
        __builtin_amdgcn_s_barrier();
        __builtin_amdgcn_sched_barrier(0);
#pragma unroll
        for (int s = 0; s < 2; ++s) {
          bf16x8 af = *(const bf16x8*)&vL[(wr * 16 + rr) * 264 + k0 + s * 32 + g8];
          bf16x8 bfr[4];
#pragma unroll
          for (int ni = 0; ni < 4; ++ni)
            bfr[ni] = breadB(cur, wc * 64 + ni * 16 + rr, s);
#pragma unroll
          for (int ni = 0; ni < 4; ++ni)
            acc1[ni] = __builtin_amdgcn_mfma_f32_16x16x32_bf16(af, bfr[ni], acc1[ni], 0, 0, 0);
        }
        __builtin_amdgcn_sched_barrier(0);
        __builtin_amdgcn_s_barrier();
        cur ^= 1;
      }
    }
#pragma unroll
    for (int ni = 0; ni < 4; ++ni) {
      float bb = b1[nb * 256 + col[ni]];
#pragma unroll
      for (int r = 0; r < 4; ++r) {
        int lrow = wr * 16 + g4 + r;
        hch[lrow * 264 + col[ni]] = (bf16)fmaxf(acc1[ni][r] + bb, 0.f);
      }
    }
    __syncthreads();

    // FFN2 partial: acc2 += hch @ W2[:, nb-slice]; K=256, BK=64
    stageB(W2b, strideW2, 0, nb * 256, 0);
    {
      int cur = 0;
      for (int k0 = 0; k0 < 256; k0 += 64) {
        const bool pf = (k0 + 64 < 256);
        if (pf) {
          stageB(W2b, strideW2, 0, nb * 256 + k0 + 64, cur ^ 1);
          asm volatile("s_waitcnt vmcnt(2)" ::: "memory");
        } else {
          asm volatile("s_waitcnt vmcnt(0)" ::: "memory");
        }
        __builtin_amdgcn_s_barrier();
        __builtin_amdgcn_sched_barrier(0);
#pragma unroll
        for (int s = 0; s < 2; ++s) {
          bf16x8 af = *(const bf16x8*)&hch[(wr * 16 + rr) * 264 + k0 + s * 32 + g8];
          bf16x8 bfr[4];
#pragma unroll
          for (int ni = 0; ni < 4; ++ni)
            bfr[ni] = breadB(cur, wc * 64 + ni * 16 + rr, s);
#pragma unroll
          for (int ni = 0; ni < 4; ++ni)
            acc2[ni] = __builtin_amdgcn_mfma_f32_16x16x32_bf16(af, bfr[ni], acc2[ni], 0, 0, 0);
        }
        __builtin_amdgcn_sched_barrier(0);
        __builtin_amdgcn_s_barrier();
        cur ^= 1;
      }
    }
    __syncthreads();   // hch will be overwritten next nb
  }

  // ---------------- LN2 over y + f ----------------
  {
    float bv[4], scv[4], biv[4];
#pragma unroll
    for (int ni = 0; ni < 4; ++ni) {
      bv[ni] = b2[col[ni]];
      scv[ni] = ln2s[col[ni]];
      biv[ni] = ln2b[col[ni]];
    }
    float v[4][4];
#pragma unroll
    for (int r = 0; r < 4; ++r)
#pragma unroll
      for (int ni = 0; ni < 4; ++ni)
        v[ni][r] = y[ni][r] + acc2[ni][r] + bv[ni];
#pragma unroll
    for (int r = 0; r < 4; ++r) {
      float s1 = (v[0][r] + v[1][r]) + (v[2][r] + v[3][r]);
      float s2 = (v[0][r] * v[0][r] + v[1][r] * v[1][r]) + (v[2][r] * v[2][r] + v[3][r] * v[3][r]);
#pragma unroll
      for (int off = 8; off; off >>= 1) {
        s1 += __shfl_xor(s1, off);
        s2 += __shfl_xor(s2, off);
      }
      if (rr == 0) {
        wsum[wid][g4 + r][0] = s1;
        wsum[wid][g4 + r][1] = s2;
      }
    }
    __syncthreads();
    if (tid < 64) {
      int row = tid;
      int band = row >> 4;
      float s1 = 0.f, s2 = 0.f;
#pragma unroll
      for (int k = 0; k < 4; ++k) {
        s1 += wsum[band * 4 + k][row & 15][0];
        s2 += wsum[band * 4 + k][row & 15][1];
      }
      float mu = s1 * (1.f / 256.f);
      float var = s2 * (1.f / 256.f) - mu * mu;
      stats[row][0] = mu;
      stats[row][1] = rsqrtf(var + 1e-5f);
    }
    __syncthreads();
#pragma unroll
    for (int r = 0; r < 4; ++r) {
      int lrow = wr * 16 + g4 + r;
      int grow = m0 + lrow;
      float mu = stats[lrow][0], rs = stats[lrow][1];
#pragma unroll
      for (int ni = 0; ni < 4; ++ni) {
        float yy = (v[ni][r] - mu) * rs * scv[ni] + biv[ni];
        out32[(size_t)grow * 256 + col[ni]] = yy;
        out16[(size_t)grow * 256 + col[ni]] = (bf16)yy;
      }
    }
  }
}

// ---------------------------------------------------------------- attention
static constexpr int LDV = 534;  // Vt row stride (bf16)
static constexpr float LOG2E = 1.4426950408889634f;
static constexpr float KSC = 0.17677669529663687f * LOG2E;  // scale * log2e

__device__ __forceinline__ int jloc(int r, int hi) { return (r & 3) + 8 * (r >> 2) + 4 * hi; }

__device__ __forceinline__ f32x16 qk_tile_g(const bf16* __restrict__ kbase, int jbase, int lq,
                                            const bf16x8& qf0, const bf16x8& qf1, int hi) {
  const bf16* kr = kbase + (size_t)(jbase + lq) * 256 + hi * 8;
  bf16x8 ka0 = *(const bf16x8*)(kr);
  bf16x8 ka1 = *(const bf16x8*)(kr + 16);
  f32x16 c = {};
  c = __builtin_amdgcn_mfma_f32_32x32x16_bf16(ka0, qf0, c, 0, 0, 0);
  c = __builtin_amdgcn_mfma_f32_32x32x16_bf16(ka1, qf1, c, 0, 0, 0);
  return c;
}

template <bool MASKED>
__device__ __forceinline__ void tileA(const f32x16& c, int jbase, int hi, int qlim, float& tot) {
  float t[4] = {0.f, 0.f, 0.f, 0.f};
#pragma unroll
  for (int q2 = 0; q2 < 4; ++q2)
#pragma unroll
    for (int p = 0; p < 4; ++p) {
      const int r = q2 * 4 + p;
      float e = __builtin_amdgcn_exp2f(c[r] * KSC);
      if (MASKED) {
        int j = jbase + 8 * q2 + 4 * hi + p;
        if (j > qlim) e = 0.f;
      }
      t[q2] += e;
    }
  tot += (t[0] + t[1]) + (t[2] + t[3]);
}

template <bool MASKED>
__device__ __forceinline__ void tileB(const f32x16& c, int jbase, int lq, int hi,
                                      int qlim, float itot, float gneg2, float posf,
                                      const bf16* Vt, float& run, float& sum2, f32x16& pvacc) {
  float su2[16], lcs[16], G[4];
#pragma unroll
  for (int q2 = 0; q2 < 4; ++q2) {
    float a = 0.f;
#pragma unroll
    for (int p = 0; p < 4; ++p) {
      const int r = q2 * 4 + p;
      su2[r] = c[r] * KSC;
      float e = __builtin_amdgcn_exp2f(su2[r]);
      if (MASKED) {
        int j = jbase + 8 * q2 + 4 * hi + p;
        if (j > qlim) e = 0.f;
      }
      a += e;
      lcs[r] = a;
    }
    G[q2] = a;
  }
  float Po[4];
#pragma unroll
  for (int q2 = 0; q2 < 4; ++q2) Po[q2] = __shfl_xor(G[q2], 32);
  float base[4];
  {
    float pre = run;
#pragma unroll
    for (int q2 = 0; q2 < 4; ++q2) {
      base[q2] = pre + (hi ? Po[q2] : 0.f);
      pre += G[q2] + Po[q2];
    }
    run = pre;
  }
#pragma unroll
  for (int cc = 0; cc < 2; ++cc) {
    float pv[8];
#pragma unroll
    for (int q2s = 0; q2s < 2; ++q2s) {
      const int q2 = cc * 2 + q2s;
#pragma unroll
      for (int p = 0; p < 4; ++p) {
        const int r = q2 * 4 + p;
        float cum = base[q2] + lcs[r];
        float pos = posf - (float)(8 * q2 + p);
        float d2 = fmaxf(__builtin_fmaf(-cum, itot, 1.f) * pos, 0.f);
        float dist = __builtin_amdgcn_sqrtf(d2);
        float eff = fmaxf(__builtin_amdgcn_exp2f(dist * gneg2), 1e-5f);
        float t = __builtin_amdgcn_exp2f(su2[r] * eff);
        if (MASKED) {
          int j = jbase + 8 * q2 + 4 * hi + p;
          if (j > qlim) t = 0.f;
        }
        pv[q2s * 4 + p] = t;
      }
    }
    sum2 += ((pv[0] + pv[1]) + (pv[2] + pv[3])) + ((pv[4] + pv[5]) + (pv[6] + pv[7]));
    u32 a0, a1, b0, b1;
    {
      bf16x2 t0 = {(bf16)pv[0], (bf16)pv[1]};
      bf16x2 t1 = {(bf16)pv[2], (bf16)pv[3]};
      bf16x2 t2 = {(bf16)pv[4], (bf16)pv[5]};
      bf16x2 t3 = {(bf16)pv[6], (bf16)pv[7]};
      a0 = __builtin_bit_cast(u32, t0);
      a1 = __builtin_bit_cast(u32, t1);
      b0 = __builtin_bit_cast(u32, t2);
      b1 = __builtin_bit_cast(u32, t3);
    }
    asm volatile("v_permlane32_swap_b32 %0, %1" : "+v"(a0), "+v"(b0));
    asm volatile("v_permlane32_swap_b32 %0, %1" : "+v"(a1), "+v"(b1));
    uint4 fq; fq.x = a0; fq.y = a1; fq.z = b0; fq.w = b1;
    bf16x8 pa = __builtin_bit_cast(bf16x8, fq);
    bf16x8 vb = *(const bf16x8*)&Vt[(size_t)lq * LDV + jbase + cc * 16 + hi * 8];
    pvacc = __builtin_amdgcn_mfma_f32_32x32x16_bf16(pa, vb, pvacc, 0, 0, 0);
  }
}

// Parity-split: block (bh, pi), 512 thr / 8 waves; wave p = wid&3,
// front = wid<4.  Pair: qbLo = pi+2p, qbHi = pi+14-2p, f = 7-2p.
// front: qbLo full + qbHi[0,f); back: qbHi[f, ntHi).  Both pi+8 tiles/pass.
// K and Q fragments read from global (L2-resident); V staged transposed.
__global__ __launch_bounds__(512, 4) void attn_kernel(
    const bf16* __restrict__ kh, const bf16* __restrict__ vh,
    const float* __restrict__ gam, bf16* __restrict__ o, int incl_diag) {
  __shared__ bf16 Vt[32 * LDV];      // 34176 B
  __shared__ float exA[4][32];
  __shared__ float exB[4][32];
  __shared__ float s2A[4][32];
  __shared__ float pvp[4][32][32];   // 16 KB

  const int tid = threadIdx.x;
  const int lane = tid & 63;
  const int wid = tid >> 6;          // 0..7
  const int bh = blockIdx.x;
  const int pi = blockIdx.y;         // parity 0/1
  const int b = bh >> 3, h = bh & 7;
  const bf16* kbase = kh + ((size_t)b * 4096 + h) * 32;
  const bf16* vbase = vh + ((size_t)b * 4096 + h) * 32;
  bf16* obase = o + ((size_t)b * 4096 + h) * 32;

  // stage V transposed: Vt[dk][j] (512 threads, 2 dk-chunks each)
  {
    int u = tid & 255;
#pragma unroll
    for (int cgi = 0; cgi < 2; ++cgi) {
      int cg = (tid >> 8) * 2 + cgi;   // 0..3
      const bf16* vb = vbase + (size_t)(2 * u) * 256 + cg * 8;
      bf16x8 r0 = *(const bf16x8*)(vb);
      bf16x8 r1 = *(const bf16x8*)(vb + 256);
#pragma unroll
      for (int e = 0; e < 8; ++e) {
        bf16x2 w2 = {r0[e], r1[e]};
        *(bf16x2*)&Vt[(size_t)(cg * 8 + e) * LDV + 2 * u] = w2;
      }
    }
  }
  __syncthreads();

  float gm = gam[h];
  float gneg = -(fmaxf(gm, 0.f) + log1pf(__expf(-fabsf(gm))));
  const float gneg2 = gneg * LOG2E;
  const int lq = lane & 31;
  const int hi = lane >> 5;

  const int p = wid & 3;
  const bool front = wid < 4;
  const int f = 7 - 2 * p;            // front's qbHi tile count
  const int qbLo = pi + 2 * p;
  const int qbHi = pi + 14 - 2 * p;
  const int ntHi = qbHi + 1;
  const int q0Hi = qbHi * 32;
  const int qrHi = q0Hi + lq;
  const int qlimHi = incl_diag ? qrHi : qrHi - 1;
  const int q0Lo = qbLo * 32;
  const int qrLo = q0Lo + lq;
  const int qlimLo = incl_diag ? qrLo : qrLo - 1;

  const bf16* qrowH = kbase + (size_t)(q0Hi + lq) * 256 + hi * 8;
  const bf16x8 qfH0 = *(const bf16x8*)(qrowH);
  const bf16x8 qfH1 = *(const bf16x8*)(qrowH + 16);

  // ---- pass A ----
  float totLo = 0.f, S = 0.f;
  if (front) {
    const bf16* qrowL = kbase + (size_t)(q0Lo + lq) * 256 + hi * 8;
    const bf16x8 qfL0 = *(const bf16x8*)(qrowL);
    const bf16x8 qfL1 = *(const bf16x8*)(qrowL + 16);
    for (int jt = 0; jt < qbLo; ++jt) {
      f32x16 c = qk_tile_g(kbase, jt * 32, lq, qfL0, qfL1, hi);
      tileA<false>(c, jt * 32, hi, qlimLo, totLo);
    }
    {
      f32x16 c = qk_tile_g(kbase, q0Lo, lq, qfL0, qfL1, hi);
      tileA<true>(c, q0Lo, hi, qlimLo, totLo);
    }
    totLo += __shfl_xor(totLo, 32);
    for (int jt = 0; jt < f; ++jt) {
      f32x16 c = qk_tile_g(kbase, jt * 32, lq, qfH0, qfH1, hi);
      tileA<false>(c, jt * 32, hi, qlimHi, S);
    }
    S += __shfl_xor(S, 32);
    if (lane < 32) exA[p][lq] = S;
  } else {
    for (int jt = f; jt < ntHi - 1; ++jt) {
      f32x16 c = qk_tile_g(kbase, jt * 32, lq, qfH0, qfH1, hi);
      tileA<false>(c, jt * 32, hi, qlimHi, S);
    }
    {
      f32x16 c = qk_tile_g(kbase, q0Hi, lq, qfH0, qfH1, hi);
      tileA<true>(c, q0Hi, hi, qlimHi, S);
    }
    S += __shfl_xor(S, 32);
    if (lane < 32) exB[p][lq] = S;
  }
  __syncthreads();
  const float SA = exA[p][lq];
  const float SB = exB[p][lq];
  const float totHi = SA + SB;
  const float itotHi = totHi > 0.f ? 1.f / totHi : 0.f;

  // ---- pass B ----
  f32x16 pvHi = {};
  float sum2Hi = 0.f;
  if (front) {
    const bf16* qrowL = kbase + (size_t)(q0Lo + lq) * 256 + hi * 8;
    const bf16x8 qfL0 = *(const bf16x8*)(qrowL);
    const bf16x8 qfL1 = *(const bf16x8*)(qrowL + 16);
    const float itotLo = totLo > 0.f ? 1.f / totLo : 0.f;
    f32x16 pvLo = {};
    float sum2Lo = 0.f, run = 0.f;
    float posf = (float)(qrLo - 4 * hi);
    for (int jt = 0; jt < qbLo; ++jt) {
      f32x16 c = qk_tile_g(kbase, jt * 32, lq, qfL0, qfL1, hi);
      tileB<false>(c, jt * 32, lq, hi, qlimLo, itotLo, gneg2, posf, Vt, run, sum2Lo, pvLo);
      posf -= 32.f;
    }
    {
      f32x16 c = qk_tile_g(kbase, q0Lo, lq, qfL0, qfL1, hi);
      tileB<true>(c, q0Lo, lq, hi, qlimLo, itotLo, gneg2, posf, Vt, run, sum2Lo, pvLo);
    }
    sum2Lo += __shfl_xor(sum2Lo, 32);
    const float inv2Lo = sum2Lo > 0.f ? 1.f / sum2Lo : 0.f;
#pragma unroll
    for (int r = 0; r < 16; ++r) {
      int qv = jloc(r, hi);
      float iv = __shfl(inv2Lo, qv);
      obase[(size_t)(q0Lo + qv) * 256 + lq] = (bf16)(pvLo[r] * iv);
    }
    run = 0.f;
    posf = (float)(qrHi - 4 * hi);
    for (int jt = 0; jt < f; ++jt) {
      f32x16 c = qk_tile_g(kbase, jt * 32, lq, qfH0, qfH1, hi);
      tileB<false>(c, jt * 32, lq, hi, qlimHi, itotHi, gneg2, posf, Vt, run, sum2Hi, pvHi);
      posf -= 32.f;
    }
    sum2Hi += __shfl_xor(sum2Hi, 32);
    if (lane < 32) s2A[p][lq] = sum2Hi;
#pragma unroll
    for (int r = 0; r < 16; ++r) pvp[p][jloc(r, hi)][lq] = pvHi[r];
  } else {
    float run = SA;
    float posf = (float)(qrHi - 4 * hi - 32 * f);
    for (int jt = f; jt < ntHi - 1; ++jt) {
      f32x16 c = qk_tile_g(kbase, jt * 32, lq, qfH0, qfH1, hi);
      tileB<false>(c, jt * 32, lq, hi, qlimHi, itotHi, gneg2, posf, Vt, run, sum2Hi, pvHi);
      posf -= 32.f;
    }
    {
      f32x16 c = qk_tile_g(kbase, q0Hi, lq, qfH0, qfH1, hi);
      tileB<true>(c, q0Hi, lq, hi, qlimHi, itotHi, gneg2, posf, Vt, run, sum2Hi, pvHi);
    }
    sum2Hi += __shfl_xor(sum2Hi, 32);
  }
  __syncthreads();
  if (!front) {
    const float s2 = s2A[p][lq] + sum2Hi;
    const float inv2 = s2 > 0.f ? 1.f / s2 : 0.f;
#pragma unroll
    for (int r = 0; r < 16; ++r) {
      int qv = jloc(r, hi);
      float iv = __shfl(inv2, qv);
      float val = pvHi[r] + pvp[p][qv][lq];
      obase[(size_t)(q0Hi + qv) * 256 + lq] = (bf16)(val * iv);
    }
  }
}

// ---------------------------------------------------------------- host
extern "C" void kernel_launch(void* const* d_in, const int* in_sizes, int n_in,
                              void* d_out, int out_size, void* d_ws, size_t ws_size,
                              hipStream_t stream) {
  const float* q_embed  = (const float*)d_in[0];
  const float* qa_embed = (const float*)d_in[1];
  const float* Wk = (const float*)d_in[2];
  const float* bk = (const float*)d_in[3];
  const float* Wv = (const float*)d_in[4];
  const float* bv = (const float*)d_in[5];
  const float* Wo = (const float*)d_in[6];
  const float* bo = (const float*)d_in[7];
  const float* gammas = (const float*)d_in[8];
  const float* ln1_s = (const float*)d_in[9];
  const float* ln1_b = (const float*)d_in[10];
  const float* W1 = (const float*)d_in[11];
  const float* b1 = (const float*)d_in[12];
  const float* W2 = (const float*)d_in[13];
  const float* b2 = (const float*)d_in[14];
  const float* ln2_s = (const float*)d_in[15];
  const float* ln2_b = (const float*)d_in[16];
  float* out = (float*)d_out;

  char* ws = (char*)d_ws;
  float* y32 = (float*)(ws);
  float* x32 = (float*)(ws + ((size_t)16 << 20));
  bf16* y16  = (bf16*)(ws + ((size_t)32 << 20));
  bf16* x16  = (bf16*)(ws + ((size_t)40 << 20));
  bf16* khb  = (bf16*)(ws + ((size_t)48 << 20));
  bf16* vhb  = (bf16*)(ws + ((size_t)56 << 20));
  bf16* o16  = (bf16*)(ws + ((size_t)64 << 20));
  bf16* Wkt  = (bf16*)(ws + ((size_t)122 << 20));
  bf16* Wvt  = Wkt + 6 * 65536;
  bf16* Wot  = Wvt + 6 * 65536;
  bf16* W1t  = Wot + 6 * 65536;      // [N=1024][K=256] per layer
  bf16* W2t  = W1t + 6 * 262144;     // [N=256][K=1024] per layer

  transpose_cvt_all<<<dim3(16, 16, 30), 256, 0, stream>>>(Wk, Wv, Wo, W1, W2,
                                                          Wkt, Wvt, Wot, W1t, W2t);
  cvt_copy2_kernel<<<dim3(4096, 2), 256, 0, stream>>>(q_embed, x32, x16,
                                                      qa_embed, y32, y16, Mc * 256 / 4);

  for (int i = 0; i < 6; ++i) {
    const bool first = (i < 2);
    const bool strict = (i == 3 || i == 5);   // mask_flag==0 layers
    const bool pos = first || strict;         // apply_pos
    bf16* in16 = first ? y16 : x16;           // q/k input (kq_same)
    bf16* v16  = (first || strict) ? y16 : x16;
    float* res32 = first ? y32 : x32;

    gemm_kv_kernel<<<dim3(128, 4), 256, 0, stream>>>(
        in16, Wkt + (size_t)i * 65536, bk + i * 256, khb,
        v16, Wvt + (size_t)i * 65536, bv + i * 256, vhb, 256, 256);
    attn_kernel<<<dim3(256, 2), 512, 0, stream>>>(khb, vhb, gammas + i * 8, o16, strict ? 0 : 1);
    if (pos) {
      float* fin = (i == 5) ? out : res32;
      gemm_ln_ffn_kernel<<<256, 1024, 0, stream>>>(
          o16, Wot + (size_t)i * 65536, bo + i * 256, res32,
          ln1_s + i * 256, ln1_b + i * 256,
          W1t + (size_t)i * 262144, b1 + i * 1024,
          W2t + (size_t)i * 262144, b2 + i * 256,
          ln2_s + i * 256, ln2_b + i * 256, fin, in16);
    } else {
      gemm_ln_kernel<256><<<512, 512, 0, stream>>>(
          o16, Wot + (size_t)i * 65536, bo + i * 256, res32,
          ln1_s + i * 256, ln1_b + i * 256, res32, in16);
    }
  }
}